// Round 5
// baseline (227.200 us; speedup 1.0000x reference)
//
#include <hip/hip_runtime.h>
#include <stdint.h>

#define IN_F   4096
#define OUT_F  4096
#define M_TOT  512
#define KT     (IN_F / 32)      // 128 global 32-wide k-steps
#define BN     64               // weight rows per block
#define BK     64               // K per staging iteration
#define KSPLIT 4
#define KPB    (IN_F / KSPLIT)  // 1024 K per block
#define NITER  (KPB / BK)       // 16 iterations
#define PF     4                // prefetch ring depth

typedef unsigned short u16;
typedef __bf16 bf16x8 __attribute__((ext_vector_type(8)));
typedef float  f32x4  __attribute__((ext_vector_type(4)));
typedef int    i32x4  __attribute__((ext_vector_type(4)));
typedef float  fv4    __attribute__((ext_vector_type(4)));

__device__ __forceinline__ u16 f2bf(float x) {
    unsigned u = __float_as_uint(x);
    u += 0x7FFFu + ((u >> 16) & 1u);   // round-to-nearest-even
    return (u16)(u >> 16);
}

// Workgroup barrier that drains ONLY LDS ops (lgkmcnt), not the global-load
// queue. Legal here because staged global loads land in private VGPRs; only
// the ds_writes need cross-wave visibility. This keeps HBM prefetches in
// flight across the barrier (the vmcnt(0)-drain was R1-R4's limiter).
__device__ __forceinline__ void lds_barrier() {
    asm volatile("s_waitcnt lgkmcnt(0)\n\ts_barrier" ::: "memory");
}

// ---- pass 0: input fp32 -> bf16, MFMA-A-fragment order in workspace ----
// aws[((mt*KT + kt)*64 + lane)*8 + j] = in[mt*16 + (lane&15)][kt*32 + (lane>>4)*8 + j]
__global__ void pack_a_kernel(const float* __restrict__ in, u16* __restrict__ aws) {
    int t    = blockIdx.x * blockDim.x + threadIdx.x;  // 262144 threads
    int lane = t & 63;
    int kt   = (t >> 6) & (KT - 1);
    int mt   = t >> 13;
    int m = mt * 16 + (lane & 15);
    int k = kt * 32 + ((lane >> 4) << 3);
    const float* src = in + (size_t)m * IN_F + k;
    float4 a0 = *(const float4*)src;
    float4 a1 = *(const float4*)(src + 4);
    union { u16 u[8]; uint4 v; } pk;
    pk.u[0]=f2bf(a0.x); pk.u[1]=f2bf(a0.y); pk.u[2]=f2bf(a0.z); pk.u[3]=f2bf(a0.w);
    pk.u[4]=f2bf(a1.x); pk.u[5]=f2bf(a1.y); pk.u[6]=f2bf(a1.z); pk.u[7]=f2bf(a1.w);
    *(uint4*)(aws + (size_t)t * 8) = pk.v;
}

// ---- main: fused dequant + GEMM; 256 blocks (64 n-tiles x 4 k-quarters), 1024 thr
// BM=512 (weights read exactly once), BN=64, NT weight stream, 4-deep prefetch
// ring, lgkm-only barrier so the HBM pipeline never drains.
__global__ __launch_bounds__(1024, 4) void qlinear_kernel(
    const u16*   __restrict__ aws,
    const int*   __restrict__ qw,
    const float* __restrict__ scales,
    const float* __restrict__ zeros,
    const float* __restrict__ outlier,
    const float* __restrict__ grad,
    float*       __restrict__ part)           // [KSPLIT][512][4096]
{
    // buffer = 8 frags (ks*4+nf) x 64 lanes x 8 bf16 = 8 KB; double-buffered 16 KB
    __shared__ __align__(16) u16 Bsh[2][8 * 64 * 8];

    const int tid  = threadIdx.x;
    const int lane = tid & 63;
    const int wv   = tid >> 6;                // 0..15, m-stripe [wv*32, +32)

    const int nblk = blockIdx.x >> 2;
    const int kq   = blockIdx.x & 3;
    const int n0   = nblk * BN;
    const int k0   = kq * KPB;

    // ---- staging role: thread covers weight row (n0+srow), 4-wide k-chunk ----
    const int srow = tid >> 4;                // 0..63
    const int schk = tid & 15;                // k_local = schk*4 (0..63)
    const int orow = n0 + srow;
    const float sr = scales[orow];
    const float c0 = -zeros[orow] * sr;       // w = q*s + (o*g - z*s)
    const size_t sg = (size_t)orow * IN_F + k0 + schk * 4;
    // B-frag coords (layout verified R1/R3/R4): frag = ks*4+nf, lane = (n&15)|(quad<<4)
    const int sks   = schk >> 3;
    const int squad = (schk >> 1) & 3;
    const int j0    = (schk & 1) * 4;
    const int snf   = srow >> 4;
    const int slane = (srow & 15) | (squad << 4);
    const int doff  = ((sks * 4 + snf) * 64 + slane) * 8 + j0;

    i32x4 qb[PF]; fv4 ob[PF], gb[PF];
    auto ld = [&](int it) {
        int s = it & (PF - 1);
        size_t off = sg + (size_t)it * BK;
        qb[s] = __builtin_nontemporal_load((const i32x4*)(qw      + off));
        ob[s] = __builtin_nontemporal_load((const fv4*)  (outlier + off));
        gb[s] = __builtin_nontemporal_load((const fv4*)  (grad    + off));
    };
    auto st = [&](int it) {
        int s = it & (PF - 1);
        union { u16 u[4]; uint2 v; } pk;
        pk.u[0] = f2bf(fmaf((float)qb[s].x, sr, fmaf(ob[s].x, gb[s].x, c0)));
        pk.u[1] = f2bf(fmaf((float)qb[s].y, sr, fmaf(ob[s].y, gb[s].y, c0)));
        pk.u[2] = f2bf(fmaf((float)qb[s].z, sr, fmaf(ob[s].z, gb[s].z, c0)));
        pk.u[3] = f2bf(fmaf((float)qb[s].w, sr, fmaf(ob[s].w, gb[s].w, c0)));
        *(uint2*)(&Bsh[it & 1][doff]) = pk.v;
    };

    // A fragment base: frag (mf, d) at abase + (mf*KT + d)*512, d = global 32-k step
    const u16* abase = aws + ((size_t)(wv * 2) * KT + kq * (KPB / 32)) * 512
                           + (size_t)lane * 8;

    f32x4 acc[2][4] = {};

    ld(0); ld(1); ld(2); ld(3);
    st(0);
    lds_barrier();

    for (int it = 0; it < NITER; ++it) {
        // A loads first (longest latency), temporal — L2-resident
        bf16x8 af[2][2];
        #pragma unroll
        for (int ks = 0; ks < 2; ++ks)
            #pragma unroll
            for (int mf = 0; mf < 2; ++mf)
                af[ks][mf] = *(const bf16x8*)(abase + ((size_t)mf * KT + it * 2 + ks) * 512);

        const u16* bb = &Bsh[it & 1][0];
        #pragma unroll
        for (int ks = 0; ks < 2; ++ks) {
            bf16x8 bfr[4];
            #pragma unroll
            for (int nf = 0; nf < 4; ++nf)
                bfr[nf] = *(const bf16x8*)(bb + (((ks * 4 + nf) * 64) + lane) * 8);
            #pragma unroll
            for (int mf = 0; mf < 2; ++mf)
                #pragma unroll
                for (int nf = 0; nf < 4; ++nf)
                    acc[mf][nf] = __builtin_amdgcn_mfma_f32_16x16x32_bf16(
                        af[ks][mf], bfr[nf], acc[mf][nf], 0, 0, 0);
        }

        if (it + 1 < NITER) st(it + 1);       // data from ld(it+1), long in flight
        if (it + PF < NITER) ld(it + PF);     // keep PF*48B/thread outstanding
        lds_barrier();
    }

    // ---- epilogue: fp32 partials, non-temporal (write-once-read-once) ----
    float* pout = part + (size_t)kq * (M_TOT * OUT_F);
    const int cm0 = wv * 32 + ((lane >> 4) << 2);
    const int cn  = n0 + (lane & 15);
    #pragma unroll
    for (int mf = 0; mf < 2; ++mf)
        #pragma unroll
        for (int nf = 0; nf < 4; ++nf)
            #pragma unroll
            for (int r = 0; r < 4; ++r)
                __builtin_nontemporal_store(
                    acc[mf][nf][r],
                    pout + (size_t)(cm0 + mf * 16 + r) * OUT_F + cn + nf * 16);
}

// ---- reduce: out = bias + sum_k partial[k] ----
__global__ void reduce_kernel(const fv4* __restrict__ part,
                              const fv4* __restrict__ bias,
                              fv4* __restrict__ out) {
    int idx = blockIdx.x * blockDim.x + threadIdx.x;   // 524288
    fv4 s = bias[idx & (OUT_F / 4 - 1)];
    const int STRIDE = M_TOT * OUT_F / 4;
    #pragma unroll
    for (int k = 0; k < KSPLIT; ++k) {
        fv4 p = __builtin_nontemporal_load(part + (size_t)k * STRIDE + idx);
        s += p;
    }
    out[idx] = s;
}

extern "C" void kernel_launch(void* const* d_in, const int* in_sizes, int n_in,
                              void* d_out, int out_size, void* d_ws, size_t ws_size,
                              hipStream_t stream) {
    const float* input   = (const float*)d_in[0];
    const int*   qweight = (const int*)  d_in[1];
    const float* scales  = (const float*)d_in[2];
    const float* zeros   = (const float*)d_in[3];
    const float* outlier = (const float*)d_in[4];
    const float* grad    = (const float*)d_in[5];
    const float* bias    = (const float*)d_in[6];
    float* out = (float*)d_out;

    u16*   aws  = (u16*)d_ws;                               // 4 MB
    float* part = (float*)((char*)d_ws + (4u << 20));       // 32 MB

    pack_a_kernel<<<(M_TOT * IN_F / 8) / 256, 256, 0, stream>>>(input, aws);
    qlinear_kernel<<<(OUT_F / BN) * KSPLIT, 1024, 0, stream>>>(
        aws, qweight, scales, zeros, outlier, grad, part);
    reduce_kernel<<<(M_TOT * OUT_F / 4) / 256, 256, 0, stream>>>(
        (const fv4*)part, (const fv4*)bias, (fv4*)out);
}